// Round 1
// baseline (1300.647 us; speedup 1.0000x reference)
//
#include <hip/hip_runtime.h>
#include <cstdint>

#define NN 100000
#define EE 3200000
#define DIM 32

// h[N,din] -> t = h@Wn  and  agg = h@Ws + bn   (single pass over h)
__global__ void k_transform(const float* __restrict__ h,
                            const float* __restrict__ Wn,
                            const float* __restrict__ Ws,
                            const float* __restrict__ bn,
                            float* __restrict__ t,
                            float* __restrict__ agg,
                            int din) {
    __shared__ float WnL[128 * 32];
    __shared__ float WsL[128 * 32];
    for (int i = threadIdx.x; i < din * 32; i += 256) {
        WnL[i] = Wn[i];
        WsL[i] = Ws[i];
    }
    __syncthreads();
    int node = blockIdx.x * 8 + (threadIdx.x >> 5);
    int d = threadIdx.x & 31;
    if (node >= NN) return;
    const float* hr = h + (size_t)node * din;
    float accn = 0.f;
    float accs = bn[d];
    for (int k = 0; k < din; ++k) {
        float f = hr[k];
        accn += f * WnL[k * 32 + d];
        accs += f * WsL[k * 32 + d];
    }
    t[node * 32 + d] = accn;
    agg[node * 32 + d] = accs;
}

// for each edge e: agg[dst[e]][:] += t[src[e]][:]
__global__ void k_edge(const int* __restrict__ src,
                       const int* __restrict__ dst,
                       const float* __restrict__ t,
                       float* __restrict__ agg) {
    int tid = blockIdx.x * blockDim.x + threadIdx.x;
    if (tid >= EE * 32) return;
    int e = tid >> 5;
    int d = tid & 31;
    int s = src[e];
    int dn = dst[e];
    atomicAdd(&agg[dn * 32 + d], t[s * 32 + d]);
}

__global__ void k_relu(const float* __restrict__ in, float* __restrict__ out, int n) {
    int i = blockIdx.x * blockDim.x + threadIdx.x;
    if (i < n) out[i] = fmaxf(in[i], 0.f);
}

// concat(x,h1,h2,h3) @ fc_w + fc_b -> log_softmax
__global__ void k_final(const float* __restrict__ x,
                        const float* __restrict__ h1,
                        const float* __restrict__ h2,
                        const float* __restrict__ h3,
                        const float* __restrict__ fc_w,
                        const float* __restrict__ fc_b,
                        float* __restrict__ out) {
    __shared__ float Wl[224 * 10];
    __shared__ float bl[10];
    for (int i = threadIdx.x; i < 224 * 10; i += blockDim.x) Wl[i] = fc_w[i];
    if (threadIdx.x < 10) bl[threadIdx.x] = fc_b[threadIdx.x];
    __syncthreads();
    int n = blockIdx.x * blockDim.x + threadIdx.x;
    if (n >= NN) return;
    float acc[10];
    #pragma unroll
    for (int c = 0; c < 10; ++c) acc[c] = bl[c];
    const float* xr = x + (size_t)n * 128;
    for (int j = 0; j < 128; ++j) {
        float f = xr[j];
        #pragma unroll
        for (int c = 0; c < 10; ++c) acc[c] += f * Wl[j * 10 + c];
    }
    const float* hs[3] = {h1, h2, h3};
    for (int l = 0; l < 3; ++l) {
        const float* hr = hs[l] + (size_t)n * 32;
        for (int j = 0; j < 32; ++j) {
            float f = hr[j];
            #pragma unroll
            for (int c = 0; c < 10; ++c) acc[c] += f * Wl[(128 + l * 32 + j) * 10 + c];
        }
    }
    float m = acc[0];
    #pragma unroll
    for (int c = 1; c < 10; ++c) m = fmaxf(m, acc[c]);
    float s = 0.f;
    #pragma unroll
    for (int c = 0; c < 10; ++c) s += __expf(acc[c] - m);
    float ls = __logf(s);
    #pragma unroll
    for (int c = 0; c < 10; ++c) out[n * 10 + c] = acc[c] - m - ls;
}

extern "C" void kernel_launch(void* const* d_in, const int* in_sizes, int n_in,
                              void* d_out, int out_size, void* d_ws, size_t ws_size,
                              hipStream_t stream) {
    const float* x   = (const float*)d_in[0];
    const int*   src = (const int*)d_in[1];
    const int*   dst = (const int*)d_in[2];
    const float* Wn[3] = {(const float*)d_in[3], (const float*)d_in[6], (const float*)d_in[9]};
    const float* bn[3] = {(const float*)d_in[4], (const float*)d_in[7], (const float*)d_in[10]};
    const float* Ws[3] = {(const float*)d_in[5], (const float*)d_in[8], (const float*)d_in[11]};
    const float* fc_w = (const float*)d_in[12];
    const float* fc_b = (const float*)d_in[13];
    float* out = (float*)d_out;

    float* w = (float*)d_ws;
    const size_t NF = (size_t)NN * 32;
    float* t   = w;
    float* agg = w + NF;
    float* h1  = w + 2 * NF;
    float* h2  = w + 3 * NF;
    float* h3  = w + 4 * NF;
    float* hbuf[3] = {h1, h2, h3};

    const int mm_blocks = (NN + 7) / 8;
    const int edge_blocks = (EE * 32) / 256;   // 400000, exact
    const int relu_blocks = (NN * 32 + 255) / 256;
    const int fin_blocks = (NN + 255) / 256;

    const float* hin = x;
    int din = 128;
    for (int l = 0; l < 3; ++l) {
        k_transform<<<mm_blocks, 256, 0, stream>>>(hin, Wn[l], Ws[l], bn[l], t, agg, din);
        k_edge<<<edge_blocks, 256, 0, stream>>>(src, dst, t, agg);
        k_relu<<<relu_blocks, 256, 0, stream>>>(agg, hbuf[l], NN * 32);
        hin = hbuf[l];
        din = 32;
    }
    k_final<<<fin_blocks, 256, 0, stream>>>(x, h1, h2, h3, fc_w, fc_b, out);
}

// Round 2
// 1161.327 us; speedup vs baseline: 1.1200x; 1.1200x over previous
//
#include <hip/hip_runtime.h>
#include <cstdint>

#define NN 100000
#define EE 3200000
#define SCAN_BLK 1024
#define NBLK ((NN + SCAN_BLK - 1) / SCAN_BLK)   // 98

// ---------------- CSR build (counting sort by dst) ----------------

__global__ void k_hist(const int* __restrict__ dst, int* __restrict__ deg) {
    int e = blockIdx.x * blockDim.x + threadIdx.x;
    if (e < EE) atomicAdd(&deg[dst[e]], 1);
}

// per-block inclusive scan of deg; emits block sums
__global__ void k_scan_partial(const int* __restrict__ deg, int* __restrict__ blocksum) {
    __shared__ int sm[SCAN_BLK];
    int i = blockIdx.x * SCAN_BLK + threadIdx.x;
    int v = (i < NN) ? deg[i] : 0;
    sm[threadIdx.x] = v;
    __syncthreads();
    // reduce to block sum
    for (int s = SCAN_BLK / 2; s > 0; s >>= 1) {
        if (threadIdx.x < s) sm[threadIdx.x] += sm[threadIdx.x + s];
        __syncthreads();
    }
    if (threadIdx.x == 0) blocksum[blockIdx.x] = sm[0];
}

// single-thread exclusive scan of 98 block sums (trivial size)
__global__ void k_scan_sums(int* __restrict__ blocksum, int n) {
    if (threadIdx.x == 0 && blockIdx.x == 0) {
        int acc = 0;
        for (int b = 0; b < n; ++b) {
            int v = blocksum[b];
            blocksum[b] = acc;
            acc += v;
        }
    }
}

// final: rowptr[i+1] = blockoff + inclusive_scan(deg)[i]; cursor[i] = exclusive
__global__ void k_scan_final(const int* __restrict__ deg,
                             const int* __restrict__ blocksum,
                             int* __restrict__ rowptr,
                             int* __restrict__ cursor) {
    __shared__ int sm[SCAN_BLK];
    int i = blockIdx.x * SCAN_BLK + threadIdx.x;
    int v = (i < NN) ? deg[i] : 0;
    sm[threadIdx.x] = v;
    __syncthreads();
    // Hillis-Steele inclusive scan
    for (int ofs = 1; ofs < SCAN_BLK; ofs <<= 1) {
        int add = (threadIdx.x >= ofs) ? sm[threadIdx.x - ofs] : 0;
        __syncthreads();
        sm[threadIdx.x] += add;
        __syncthreads();
    }
    if (i < NN) {
        int incl = blocksum[blockIdx.x] + sm[threadIdx.x];
        rowptr[i + 1] = incl;
        cursor[i] = incl - v;   // exclusive
        if (i == 0) rowptr[0] = 0;
    }
}

__global__ void k_scatter(const int* __restrict__ src, const int* __restrict__ dst,
                          int* __restrict__ cursor, int* __restrict__ csr_src) {
    int e = blockIdx.x * blockDim.x + threadIdx.x;
    if (e < EE) {
        int p = atomicAdd(&cursor[dst[e]], 1);
        csr_src[p] = src[e];
    }
}

// ---------------- GNN compute ----------------

// h[N,din] -> t = h@Wn ; hout = h@Ws + bn  (self term staged, neighbors added later)
__global__ void k_transform(const float* __restrict__ h,
                            const float* __restrict__ Wn,
                            const float* __restrict__ Ws,
                            const float* __restrict__ bn,
                            float* __restrict__ t,
                            float* __restrict__ hout,
                            int din) {
    __shared__ float WnL[128 * 32];
    __shared__ float WsL[128 * 32];
    for (int i = threadIdx.x; i < din * 32; i += 256) {
        WnL[i] = Wn[i];
        WsL[i] = Ws[i];
    }
    __syncthreads();
    int node = blockIdx.x * 8 + (threadIdx.x >> 5);
    int d = threadIdx.x & 31;
    if (node >= NN) return;
    const float* hr = h + (size_t)node * din;
    float accn = 0.f;
    float accs = bn[d];
    for (int k = 0; k < din; ++k) {
        float f = hr[k];
        accn += f * WnL[k * 32 + d];
        accs += f * WsL[k * 32 + d];
    }
    t[node * 32 + d] = accn;
    hout[node * 32 + d] = accs;
}

// hout[n][d] = relu(hout[n][d] + sum_{j in row(n)} t[csr_src[j]][d])
__global__ void k_aggregate(const int* __restrict__ rowptr,
                            const int* __restrict__ csr_src,
                            const float* __restrict__ t,
                            float* __restrict__ hout) {
    int node = blockIdx.x * 8 + (threadIdx.x >> 5);
    int d = threadIdx.x & 31;
    if (node >= NN) return;
    int start = rowptr[node];
    int end = rowptr[node + 1];
    float acc = 0.f;
    for (int j = start; j < end; ++j) {
        int s = csr_src[j];
        acc += t[s * 32 + d];
    }
    int idx = node * 32 + d;
    hout[idx] = fmaxf(hout[idx] + acc, 0.f);
}

// concat(x,h1,h2,h3) @ fc_w + fc_b -> log_softmax
__global__ void k_final(const float* __restrict__ x,
                        const float* __restrict__ h1,
                        const float* __restrict__ h2,
                        const float* __restrict__ h3,
                        const float* __restrict__ fc_w,
                        const float* __restrict__ fc_b,
                        float* __restrict__ out) {
    __shared__ float Wl[224 * 10];
    __shared__ float bl[10];
    for (int i = threadIdx.x; i < 224 * 10; i += blockDim.x) Wl[i] = fc_w[i];
    if (threadIdx.x < 10) bl[threadIdx.x] = fc_b[threadIdx.x];
    __syncthreads();
    int n = blockIdx.x * blockDim.x + threadIdx.x;
    if (n >= NN) return;
    float acc[10];
    #pragma unroll
    for (int c = 0; c < 10; ++c) acc[c] = bl[c];
    const float* xr = x + (size_t)n * 128;
    for (int j = 0; j < 128; ++j) {
        float f = xr[j];
        #pragma unroll
        for (int c = 0; c < 10; ++c) acc[c] += f * Wl[j * 10 + c];
    }
    const float* hs[3] = {h1, h2, h3};
    for (int l = 0; l < 3; ++l) {
        const float* hr = hs[l] + (size_t)n * 32;
        for (int j = 0; j < 32; ++j) {
            float f = hr[j];
            #pragma unroll
            for (int c = 0; c < 10; ++c) acc[c] += f * Wl[(128 + l * 32 + j) * 10 + c];
        }
    }
    float m = acc[0];
    #pragma unroll
    for (int c = 1; c < 10; ++c) m = fmaxf(m, acc[c]);
    float s = 0.f;
    #pragma unroll
    for (int c = 0; c < 10; ++c) s += __expf(acc[c] - m);
    float ls = __logf(s);
    #pragma unroll
    for (int c = 0; c < 10; ++c) out[n * 10 + c] = acc[c] - m - ls;
}

extern "C" void kernel_launch(void* const* d_in, const int* in_sizes, int n_in,
                              void* d_out, int out_size, void* d_ws, size_t ws_size,
                              hipStream_t stream) {
    const float* x   = (const float*)d_in[0];
    const int*   src = (const int*)d_in[1];
    const int*   dst = (const int*)d_in[2];
    const float* Wn[3] = {(const float*)d_in[3], (const float*)d_in[6], (const float*)d_in[9]};
    const float* bn[3] = {(const float*)d_in[4], (const float*)d_in[7], (const float*)d_in[10]};
    const float* Ws[3] = {(const float*)d_in[5], (const float*)d_in[8], (const float*)d_in[11]};
    const float* fc_w = (const float*)d_in[12];
    const float* fc_b = (const float*)d_in[13];
    float* out = (float*)d_out;

    // workspace layout
    char* w = (char*)d_ws;
    const size_t NF = (size_t)NN * 32;
    float* t   = (float*)w;                     w += NF * 4;          // 12.8 MB
    float* h1  = (float*)w;                     w += NF * 4;
    float* h2  = (float*)w;                     w += NF * 4;
    float* h3  = (float*)w;                     w += NF * 4;
    int* csr_src = (int*)w;                     w += (size_t)EE * 4;  // 12.8 MB
    int* deg     = (int*)w;                     w += (size_t)NN * 4;
    int* rowptr  = (int*)w;                     w += (size_t)(NN + 1) * 4;
    int* cursor  = (int*)w;                     w += (size_t)NN * 4;
    int* blocksum = (int*)w;                    w += (size_t)NBLK * 4;
    float* hbuf[3] = {h1, h2, h3};

    // ---- CSR build ----
    hipMemsetAsync(deg, 0, (size_t)NN * 4, stream);
    k_hist<<<(EE + 255) / 256, 256, 0, stream>>>(dst, deg);
    k_scan_partial<<<NBLK, SCAN_BLK, 0, stream>>>(deg, blocksum);
    k_scan_sums<<<1, 64, 0, stream>>>(blocksum, NBLK);
    k_scan_final<<<NBLK, SCAN_BLK, 0, stream>>>(deg, blocksum, rowptr, cursor);
    k_scatter<<<(EE + 255) / 256, 256, 0, stream>>>(src, dst, cursor, csr_src);

    // ---- layers ----
    const int mm_blocks = (NN + 7) / 8;
    const float* hin = x;
    int din = 128;
    for (int l = 0; l < 3; ++l) {
        k_transform<<<mm_blocks, 256, 0, stream>>>(hin, Wn[l], Ws[l], bn[l], t, hbuf[l], din);
        k_aggregate<<<mm_blocks, 256, 0, stream>>>(rowptr, csr_src, t, hbuf[l]);
        hin = hbuf[l];
        din = 32;
    }
    k_final<<<(NN + 255) / 256, 256, 0, stream>>>(x, h1, h2, h3, fc_w, fc_b, out);
}